// Round 8
// baseline (563.507 us; speedup 1.0000x reference)
//
#include <hip/hip_runtime.h>

#define STEPS   200
#define NT      199
#define BATCH   512
#define IN_DIM  784
#define OUT_DIM 10
#define NROWS   (BATCH * IN_DIM)     // 401408 (b,i) rows
#define MWORDS  8                    // bitmask words per row (256 bits, 200 used)
#define WSTR    12                   // weight LDS row stride (48 B)

// ------- Kernel A: pack x (exactly 0.0/1.0) into bits — copy-shaped -------
// One thread per (row, word): lane reads its own 128 B cache line as 8 float4
// (dense 16 B/lane), extracts bit 23 (set iff 1.0f), packs 32 t-bits, one
// coalesced dword store. 32 waves/CU, 8 loads in flight/wave: structurally
// the m13 copy ubench. Words 6 (bits 8..31) and 7 are written as 0.
__global__ __launch_bounds__(256, 8) void snn_pack(
    const float* __restrict__ x,          // [BATCH, IN_DIM, STEPS]
    unsigned int* __restrict__ mask)      // [NROWS][MWORDS]
{
    const int T    = blockIdx.x * 256 + threadIdx.x;   // < NROWS*MWORDS
    const int wd   = T & 7;
    const int rowg = T >> 3;
    const float* src = x + (size_t)rowg * STEPS + wd * 32;

    unsigned int u = 0;
    #pragma unroll
    for (int k = 0; k < 8; ++k) {
        if (wd * 32 + k * 4 < STEPS) {      // w<6 always; w==6 only k<2; w==7 never
            float4 v = *(const float4*)(src + 4 * k);
            u |= ((__float_as_uint(v.x) >> 23) & 1u) << (4 * k + 0);
            u |= ((__float_as_uint(v.y) >> 23) & 1u) << (4 * k + 1);
            u |= ((__float_as_uint(v.z) >> 23) & 1u) << (4 * k + 2);
            u |= ((__float_as_uint(v.w) >> 23) & 1u) << (4 * k + 3);
        }
    }
    mask[T] = u;
}

// ------- Kernel B: drive from bitmask + LIF scan, one block per batch -------
// 4 waves; wave wv accumulates rows [196wv, 196wv+196) linearly; lane owns 4
// time bins t0=4*lane (lanes 0..49 active). Mask words read straight from
// global (12.8 MB, L2/L3-hot; 8-lane address groups). Weights broadcast from
// LDS. LDS 37.6 + 32 KB = 69.6 KB -> 2 blocks/CU; grid 512 = all resident.
__global__ __launch_bounds__(256) void snn_drive_scan(
    const unsigned int* __restrict__ mask,  // [NROWS][MWORDS]
    const float* __restrict__ w,            // [OUT_DIM, IN_DIM]
    float* __restrict__ out)                // [BATCH, OUT_DIM]
{
    __shared__ float w_lds[IN_DIM * WSTR];        // 37.6 KB
    __shared__ float pw[4 * OUT_DIM * STEPS];     // 32 KB, [wave][o][t]

    const int b    = blockIdx.x;
    const int tid  = threadIdx.x;
    const int wv   = tid >> 6;
    const int lane = tid & 63;
    const int t0   = lane * 4;

    for (int idx = tid; idx < IN_DIM * OUT_DIM; idx += 256) {
        int o = idx / IN_DIM;
        int i = idx - o * IN_DIM;
        w_lds[i * WSTR + o] = w[idx];
    }
    __syncthreads();

    float2 acc[4][5];     // [t-quad][o-pair]
    #pragma unroll
    for (int q = 0; q < 4; ++q)
        #pragma unroll
        for (int j = 0; j < 5; ++j) acc[q][j] = make_float2(0.0f, 0.0f);

    const int i0 = wv * 196;
    // lane's word column: t0>>5 (lanes 50..63 read words 6..7 = zeros, in-bounds)
    const unsigned int* mrow = mask + ((size_t)b * IN_DIM + i0) * MWORDS + (t0 >> 5);
    const int sh = t0 & 31;

    #define CONSUME(M, r)                                                        \
        do {                                                                     \
            const unsigned int bits = ((M) >> sh) & 15u;                         \
            const float4 w0 = *(const float4*)&w_lds[(i0 + (r)) * WSTR + 0];     \
            const float4 w1 = *(const float4*)&w_lds[(i0 + (r)) * WSTR + 4];     \
            const float2 w2 = *(const float2*)&w_lds[(i0 + (r)) * WSTR + 8];     \
            _Pragma("unroll")                                                    \
            for (int q = 0; q < 4; ++q) {                                        \
                const float xq = (float)((bits >> q) & 1u);                      \
                acc[q][0].x = fmaf(xq, w0.x, acc[q][0].x);                       \
                acc[q][0].y = fmaf(xq, w0.y, acc[q][0].y);                       \
                acc[q][1].x = fmaf(xq, w0.z, acc[q][1].x);                       \
                acc[q][1].y = fmaf(xq, w0.w, acc[q][1].y);                       \
                acc[q][2].x = fmaf(xq, w1.x, acc[q][2].x);                       \
                acc[q][2].y = fmaf(xq, w1.y, acc[q][2].y);                       \
                acc[q][3].x = fmaf(xq, w1.z, acc[q][3].x);                       \
                acc[q][3].y = fmaf(xq, w1.w, acc[q][3].y);                       \
                acc[q][4].x = fmaf(xq, w2.x, acc[q][4].x);                       \
                acc[q][4].y = fmaf(xq, w2.y, acc[q][4].y);                       \
            }                                                                    \
        } while (0)

    // 196 rows, rolling depth-4 word prefetch, ascending i (deterministic).
    unsigned int M0 = mrow[0 * 8], M1 = mrow[1 * 8], M2 = mrow[2 * 8], M3 = mrow[3 * 8];
    for (int r = 0; r < 192; r += 4) {
        unsigned int N0 = mrow[(r + 4) * 8], N1 = mrow[(r + 5) * 8];
        unsigned int N2 = mrow[(r + 6) * 8], N3 = mrow[(r + 7) * 8];
        CONSUME(M0, r + 0);
        CONSUME(M1, r + 1);
        CONSUME(M2, r + 2);
        CONSUME(M3, r + 3);
        M0 = N0; M1 = N1; M2 = N2; M3 = N3;
    }
    CONSUME(M0, 192);
    CONSUME(M1, 193);
    CONSUME(M2, 194);
    CONSUME(M3, 195);
    #undef CONSUME

    // Wave partial -> LDS [wv][o][t] (b128, conflict-free); guard t0<200.
    if (t0 < STEPS) {
        #pragma unroll
        for (int j = 0; j < 5; ++j) {
            float4 v0 = make_float4(acc[0][j].x, acc[1][j].x, acc[2][j].x, acc[3][j].x);
            float4 v1 = make_float4(acc[0][j].y, acc[1][j].y, acc[2][j].y, acc[3][j].y);
            *(float4*)&pw[(wv * OUT_DIM + 2 * j    ) * STEPS + t0] = v0;
            *(float4*)&pw[(wv * OUT_DIM + 2 * j + 1) * STEPS + t0] = v1;
        }
    }
    __syncthreads();

    // Merge 4 wave-partials (ascending wave = ascending rows) + LIF scan.
    if (tid < OUT_DIM) {
        const int o = tid;
        const float a_m = 0.995f;   // 1 - DT/TAU_M
        const float b_m = 0.005f;   // DT/TAU_M
        const float a_s = 0.98f;    // 1 - DT/TAU_S

        float V = 0.0f, I = 0.0f;
        int fst = 0;
        for (int s = 0; s < NT; ++s) {
            float drv = ((pw[(0 * OUT_DIM + o) * STEPS + s]
                        + pw[(1 * OUT_DIM + o) * STEPS + s])
                        + pw[(2 * OUT_DIM + o) * STEPS + s])
                        + pw[(3 * OUT_DIM + o) * STEPS + s];
            float Vn = a_m * V + b_m * I;   // old I, per reference ordering
            I = a_s * I + drv;
            if (Vn > 1.0f) {
                if (fst == 0) fst = s + 1;  // +1: output zero-padded at t=0
                V = 0.0f;
            } else {
                V = Vn;
            }
        }
        out[b * OUT_DIM + o] = (fst == 0) ? (float)(STEPS - 1) : (float)fst;
    }
}

extern "C" void kernel_launch(void* const* d_in, const int* in_sizes, int n_in,
                              void* d_out, int out_size, void* d_ws, size_t ws_size,
                              hipStream_t stream) {
    const float* x = (const float*)d_in[0];     // [512, 784, 200] fp32
    const float* w = (const float*)d_in[1];     // [10, 784] fp32
    float* out = (float*)d_out;                 // [512, 10] fp32
    unsigned int* mask = (unsigned int*)d_ws;   // [401408][8] u32 = 12.8 MB

    snn_pack<<<dim3(NROWS * MWORDS / 256), dim3(256), 0, stream>>>(x, mask);
    snn_drive_scan<<<dim3(BATCH), dim3(256), 0, stream>>>(mask, w, out);
}